// Round 18
// baseline (3621.030 us; speedup 1.0000x reference)
//
#include <hip/hip_runtime.h>
#include <hip/hip_bf16.h>

// Cos_RootHist_GLM — f32 in/out (passing since round 10, absmax 0.125).
// R18: scan uses VOLATILE LDS loads (compiler-tracked -> counted lgkmcnt
// waits are inserted by SIInsertWaitcnts, correctness guaranteed) with the
// straight-line 8-group subchunk. volatile defeats the rematerialization
// that flattened R14/R15's pipelines; inline-asm waits (R16/R17) are
// abandoned — compiler-invisible pending registers caused stale reads.

#define DEVINL __device__ __forceinline__

using f32x4 = __attribute__((ext_vector_type(4))) float;

static constexpr int T_DATA = 20000;
static constexpr int N_E = 2000;
static constexpr int N_I = 500;
static constexpr int SUB = 15;
static constexpr int T_NO = 200;
static constexpr int NB = 19;

// ws layout (f32 offsets) — total 670720 f32 = 2.683 MB
static constexpr int EKT_OFF = 0;       // [200][16] e-kern transposed
static constexpr int IKT_OFF = 3200;    // [200][16]
static constexpr int HT_OFF  = 6400;    // 256
static constexpr int PRM_OFF = 6656;    // 0..14 wsub2, 16..30 theta, 33 scale, 34 vo
static constexpr int WE_OFF  = 6720;    // 2000
static constexpr int WI_OFF  = 8720;    // 500
static constexpr int IDXE_B  = 36880;   // byte off, 2000 uchar
static constexpr int IDXI_B  = 38880;   // byte off, 500 uchar
static constexpr int BT_OFF  = 9856;    // 20736 (zero-padded past 20000)
static constexpr int SYNE_OFF = 30720;  // [20000][16]
static constexpr int SYNI_OFF = 350720; // [20000][16]
static constexpr int WS_END  = 670720;

DEVINL float fast_exp2(float x) {
#if __has_builtin(__builtin_amdgcn_exp2f)
  return __builtin_amdgcn_exp2f(x);
#else
  return exp2f(x);
#endif
}
DEVINL float fast_log2(float x) {
#if __has_builtin(__builtin_amdgcn_logf)
  return __builtin_amdgcn_logf(x);
#else
  return log2f(x);
#endif
}
DEVINL float rlane(float v, int l) {
  return __builtin_bit_cast(float, __builtin_amdgcn_readlane(__builtin_bit_cast(int, v), l));
}

DEVINL float softplus_f(float x) {
  float z = x * 1.44269504088896f;
  float l = 0.6931471805599453f * fast_log2(1.0f + fast_exp2(z));
  return (x > 16.0f) ? x : l;
}

// ---------------- prep ----------------
__global__ __launch_bounds__(256) void prep_kernel(
    const float* __restrict__ Cse, const float* __restrict__ Csi,
    const float* __restrict__ cosb, const float* __restrict__ Wsyn,
    const float* __restrict__ Wsub, const float* __restrict__ Vo,
    const float* __restrict__ Theta, const float* __restrict__ Whist,
    float* __restrict__ ws, float* __restrict__ outF) {
  const int tid = threadIdx.x;
  float* ekT = ws + EKT_OFF;
  float* ikT = ws + IKT_OFF;
  float* ht  = ws + HT_OFF;
  float* prm = ws + PRM_OFF;
  float* we  = ws + WE_OFF;
  float* wi  = ws + WI_OFF;
  unsigned char* idxe = (unsigned char*)ws + IDXE_B;
  unsigned char* idxi = (unsigned char*)ws + IDXI_B;
  float* bT  = ws + BT_OFF;

  for (int p = tid; p < SUB * T_NO; p += 256) {
    int s = p / T_NO, j = p - s * T_NO;
    float ae = 0.f, ai = 0.f;
    for (int b = 0; b < NB; ++b) {
      float cb = cosb[b * T_NO + j];
      ae = fmaf(Wsyn[(s * NB + b) * 2 + 0], cb, ae);
      ai = fmaf(Wsyn[(s * NB + b) * 2 + 1], cb, ai);
    }
    ekT[j * 16 + s] = ae;
    ikT[j * 16 + s] = ai;
    outF[p] = ae;
    outF[SUB * T_NO + p] = ai;
  }
  for (int j = tid; j < T_NO; j += 256) { ekT[j * 16 + 15] = 0.f; ikT[j * 16 + 15] = 0.f; }
  if (tid < 256) {
    float hv = 0.f;
    if (tid < T_NO) {
      for (int b = 0; b < NB; ++b) hv = fmaf(Whist[b], cosb[b * T_NO + tid], hv);
      outF[30 * T_NO + tid] = hv;
    }
    ht[tid] = (tid < T_NO) ? hv : 0.f;   // ht[0] == hist[0] == 0 exactly
  }
  for (int n = tid; n < N_E; n += 256) {
    int id = 0; float w = 0.f;
    for (int s = 0; s < SUB; ++s) { float c = Cse[s * N_E + n]; if (c != 0.f) { id = s; w = c; } }
    idxe[n] = (unsigned char)id; we[n] = w;
  }
  for (int n = tid; n < N_I; n += 256) {
    int id = 0; float w = 0.f;
    for (int s = 0; s < SUB; ++s) { float c = Csi[s * N_I + n]; if (c != 0.f) { id = s; w = c; } }
    idxi[n] = (unsigned char)id; wi[n] = w;
  }
  if (tid < SUB) {
    float w = Wsub[tid];
    prm[tid] = w * w;
    prm[16 + tid] = Theta[tid];
  }
  if (tid == 0) {
    float w0 = Wsub[0];
    prm[33] = w0 * w0;
    prm[34] = Vo[0];
  }
  for (int p = T_DATA + tid; p < T_DATA + 736; p += 256) bT[p] = 0.f;
}

// ---------------- pool: wave per t-row, float4 loads, LDS atomics ----------------
__global__ __launch_bounds__(256) void pool_kernel(
    const float* __restrict__ Se, const float* __restrict__ Si,
    float* __restrict__ ws) {
  __shared__ float cnt[4][32];   // [wave][0:16 E | 16:32 I]
  const int lane = threadIdx.x & 63;
  const int w = threadIdx.x >> 6;
  const int t = blockIdx.x * 4 + w;
  if (lane < 32) cnt[w][lane] = 0.f;
  __syncthreads();
  const float* we = ws + WE_OFF;
  const float* wi = ws + WI_OFF;
  const unsigned int* ie = (const unsigned int*)((const char*)ws + IDXE_B);
  const unsigned int* ii = (const unsigned int*)((const char*)ws + IDXI_B);

  const float4* rowE = (const float4*)(Se + (size_t)t * N_E);   // 500 float4
#pragma unroll
  for (int k = 0; k < 8; ++k) {
    int c = k * 64 + lane;
    if (c < 500) {
      float4 v = rowE[c];
      unsigned int b = ie[c];
      if (v.x != 0.f) atomicAdd(&cnt[w][(b      ) & 0xFFu], v.x * we[c * 4 + 0]);
      if (v.y != 0.f) atomicAdd(&cnt[w][(b >>  8) & 0xFFu], v.y * we[c * 4 + 1]);
      if (v.z != 0.f) atomicAdd(&cnt[w][(b >> 16) & 0xFFu], v.z * we[c * 4 + 2]);
      if (v.w != 0.f) atomicAdd(&cnt[w][(b >> 24) & 0xFFu], v.w * we[c * 4 + 3]);
    }
  }
  const float4* rowI = (const float4*)(Si + (size_t)t * N_I);   // 125 float4
#pragma unroll
  for (int k = 0; k < 2; ++k) {
    int c = k * 64 + lane;
    if (c < 125) {
      float4 v = rowI[c];
      unsigned int b = ii[c];
      if (v.x != 0.f) atomicAdd(&cnt[w][16 + ((b      ) & 0xFFu)], v.x * wi[c * 4 + 0]);
      if (v.y != 0.f) atomicAdd(&cnt[w][16 + ((b >>  8) & 0xFFu)], v.y * wi[c * 4 + 1]);
      if (v.z != 0.f) atomicAdd(&cnt[w][16 + ((b >> 16) & 0xFFu)], v.z * wi[c * 4 + 2]);
      if (v.w != 0.f) atomicAdd(&cnt[w][16 + ((b >> 24) & 0xFFu)], v.w * wi[c * 4 + 3]);
    }
  }
  __syncthreads();
  if (lane < 16) {
    ws[SYNE_OFF + (size_t)t * 16 + lane] = cnt[w][lane];
    ws[SYNI_OFF + (size_t)t * 16 + lane] = cnt[w][16 + lane];
  }
}

// ---------------- conv + tree: transposed LDS tiles, conflict-free ----------------
__global__ __launch_bounds__(256) void conv_tree_kernel(float* __restrict__ ws,
                                                        float* __restrict__ outNs) {
  __shared__ float sE[16][272], sI[16][272];   // transposed, padded rows
  __shared__ float ekL[200 * 16], ikL[200 * 16];
  __shared__ float synR[64][16];
  const int tid = threadIdx.x;
  const int t0 = blockIdx.x * 64;

  for (int p = tid; p < 200 * 16; p += 256) { ekL[p] = ws[EKT_OFF + p]; ikL[p] = ws[IKT_OFF + p]; }
  for (int p = tid; p < 264 * 16; p += 256) {
    int o = p >> 4, s = p & 15;
    int g = t0 - 200 + o;
    bool ok = (g >= 0) && (g < T_DATA);
    sE[s][o] = ok ? ws[SYNE_OFF + (size_t)g * 16 + s] : 0.f;
    sI[s][o] = ok ? ws[SYNI_OFF + (size_t)g * 16 + s] : 0.f;
  }
  __syncthreads();
  {
    const int q = tid >> 6, i = tid & 63;
    const int s0 = q * 4;
    float ax = 0.f, ay = 0.f, az = 0.f, aw = 0.f;
    for (int j = 0; j < T_NO; ++j) {
      int o = i + 200 - j;
      float4 e = *(const float4*)&ekL[j * 16 + s0];   // wave-uniform: broadcast
      float4 k = *(const float4*)&ikL[j * 16 + s0];
      ax = fmaf(e.x, sE[s0 + 0][o], fmaf(k.x, sI[s0 + 0][o], ax));
      ay = fmaf(e.y, sE[s0 + 1][o], fmaf(k.y, sI[s0 + 1][o], ay));
      az = fmaf(e.z, sE[s0 + 2][o], fmaf(k.z, sI[s0 + 2][o], az));
      aw = fmaf(e.w, sE[s0 + 3][o], fmaf(k.w, sI[s0 + 3][o], aw));
    }
    synR[i][s0 + 0] = ax;
    synR[i][s0 + 1] = ay;
    synR[i][s0 + 2] = az;
    synR[i][s0 + 3] = aw;
  }
  __syncthreads();
  if (tid < 64) {
    int t = t0 + tid;
    if (t < T_DATA) {
      const float* prm = ws + PRM_OFF;
      float sv[16];
#pragma unroll
      for (int s = 0; s < 16; ++s) sv[s] = synR[tid][s];
      float ns[SUB];
#pragma unroll
      for (int j = SUB - 1; j >= 1; --j) {
        float x = sv[j] + prm[16 + j];
        if (2 * j + 1 < SUB) x = fmaf(prm[2 * j + 1], ns[2 * j + 1], x);
        if (2 * j + 2 < SUB) x = fmaf(prm[2 * j + 2], ns[2 * j + 2], x);
        ns[j] = softplus_f(x);
      }
      float b = sv[0] + prm[16];
      b = fmaf(prm[1], ns[1], b);
      b = fmaf(prm[2], ns[2], b);
      ws[BT_OFF + t] = b;
      outNs[(size_t)t * SUB] = 0.f;
#pragma unroll
      for (int s = 1; s < SUB; ++s) outNs[(size_t)t * SUB + s] = ns[s];
    }
  }
}

// ---------------- serial scan: pair-parallel ring-FIR, volatile-pipelined ----------------
// rt4[u*4+r] = ht[(64r-1-u)&255]; pair k reads rows 2k,2k+1 (32B).
// 8 groups of 8 volatile f32x4 loads; group g+1 issued before consuming g.
// volatile: no remat, program-order issue; compiler inserts counted lgkmcnt.
__global__ __launch_bounds__(64) void scan_kernel(const float* __restrict__ ws,
                                                  float* __restrict__ outV) {
  __shared__ __align__(16) float rt4[320 * 4];
  const int lane = threadIdx.x;
  const float* ht = ws + HT_OFF;
  const float* prm = ws + PRM_OFF;
  const float* bT = ws + BT_OFF;
  for (int p = lane; p < 320 * 4; p += 64) {
    int u = p >> 2, r = p & 3;
    rt4[p] = ht[(64 * r - 1 - u) & 255];
  }
  __syncthreads();
  const float L2E = 1.44269504088896f;
  const float scale2 = 0.6931471805599453f * prm[33];  // ln2 * wsub2[0]
  const float vo = prm[34];
  float a0 = L2E * bT[lane];          // fires in sub-chunks c==0
  float a1 = L2E * bT[64 + lane];     // c==1
  float a2 = L2E * bT[128 + lane];    // c==2
  float a3 = L2E * bT[192 + lane];    // c==3
  float cap = 0.f;
  const int myk = lane >> 1;
  const bool oddlane = (lane & 1);
  int ub = (0 - lane) & 255;
  int t0 = 0;

#define LDG(G, BASEB)                                                            \
  f32x4 G##0 = *(volatile const f32x4*)(rp + (BASEB) + 0);                       \
  f32x4 G##1 = *(volatile const f32x4*)(rp + (BASEB) + 16);                      \
  f32x4 G##2 = *(volatile const f32x4*)(rp + (BASEB) + 32);                      \
  f32x4 G##3 = *(volatile const f32x4*)(rp + (BASEB) + 48);                      \
  f32x4 G##4 = *(volatile const f32x4*)(rp + (BASEB) + 64);                      \
  f32x4 G##5 = *(volatile const f32x4*)(rp + (BASEB) + 80);                      \
  f32x4 G##6 = *(volatile const f32x4*)(rp + (BASEB) + 96);                      \
  f32x4 G##7 = *(volatile const f32x4*)(rp + (BASEB) + 112);

#define PAIR(AC, K, C0, C1)                                                      \
  {                                                                              \
    float OB0 = rlane(AC, 2 * (K));                                              \
    float OB1 = rlane(AC, 2 * (K) + 1);                                          \
    float y0 = fast_log2(1.0f + fast_exp2(OB0));                                 \
    float y1 = fast_log2(1.0f + fast_exp2(OB1));                                 \
    bool own = (myk == (K));                                                     \
    cap = own ? (oddlane ? y1 : y0) : cap;                                       \
    AC = own ? bnext : AC;                                                       \
    a0 = fmaf(C0[0], y0, a0); a0 = fmaf(C1[0], y1, a0);                          \
    a1 = fmaf(C0[1], y0, a1); a1 = fmaf(C1[1], y1, a1);                          \
    a2 = fmaf(C0[2], y0, a2); a2 = fmaf(C1[2], y1, a2);                          \
    a3 = fmaf(C0[3], y0, a3); a3 = fmaf(C1[3], y1, a3);                          \
  }

#define CONSUME4(AC, KB, G)                                                      \
  PAIR(AC, (KB) + 0, G##0, G##1)                                                 \
  PAIR(AC, (KB) + 1, G##2, G##3)                                                 \
  PAIR(AC, (KB) + 2, G##4, G##5)                                                 \
  PAIR(AC, (KB) + 3, G##6, G##7)

#define SUBCHUNK(AC, BN)                                                         \
  {                                                                              \
    const float bnext = (BN);                                                    \
    const char* rp = (const char*)rt4 + (size_t)((unsigned)ub * 16u);            \
    LDG(GA, 0)                                                                   \
    LDG(GB, 128)                                                                 \
    CONSUME4(AC, 0, GA)                                                          \
    LDG(GC, 256)                                                                 \
    CONSUME4(AC, 4, GB)                                                          \
    LDG(GD, 384)                                                                 \
    CONSUME4(AC, 8, GC)                                                          \
    LDG(GE, 512)                                                                 \
    CONSUME4(AC, 12, GD)                                                         \
    LDG(GF, 640)                                                                 \
    CONSUME4(AC, 16, GE)                                                         \
    LDG(GG, 768)                                                                 \
    CONSUME4(AC, 20, GF)                                                         \
    LDG(GH, 896)                                                                 \
    CONSUME4(AC, 24, GG)                                                         \
    CONSUME4(AC, 28, GH)                                                         \
    int t = t0 + lane;                                                           \
    if (t < T_DATA) outV[t] = fmaf(cap, scale2, vo);                             \
    ub = (ub + 64) & 255;                                                        \
    t0 += 64;                                                                    \
  }

#pragma unroll 1
  for (int g = 0; g < 78; ++g) {   // 312 chunks
    const float bn0 = L2E * bT[t0 + 256 + lane];
    const float bn1 = L2E * bT[t0 + 320 + lane];
    const float bn2 = L2E * bT[t0 + 384 + lane];
    const float bn3 = L2E * bT[t0 + 448 + lane];
    SUBCHUNK(a0, bn0)
    SUBCHUNK(a1, bn1)
    SUBCHUNK(a2, bn2)
    SUBCHUNK(a3, bn3)
  }
  {
    const float bnT = L2E * bT[t0 + 256 + lane];
    SUBCHUNK(a0, bnT)               // chunk 312 (t0 = 19968)
  }
#undef PAIR
#undef CONSUME4
#undef SUBCHUNK
#undef LDG
}

// ---------------- sentinel ----------------
__global__ __launch_bounds__(256) void sentinel_kernel(float* __restrict__ outV, int code) {
  const int tid = threadIdx.x;
  for (int t = tid; t < T_DATA; t += 256) outV[t] = (float)code;
}

extern "C" void kernel_launch(void* const* d_in, const int* in_sizes, int n_in,
                              void* d_out, int out_size, void* d_ws, size_t ws_size,
                              hipStream_t stream) {
  const float* Se    = (const float*)d_in[0];
  const float* Si    = (const float*)d_in[1];
  const float* Cse   = (const float*)d_in[3];
  const float* Csi   = (const float*)d_in[4];
  const float* cosb  = (const float*)d_in[5];
  const float* Wsyn  = (const float*)d_in[6];
  const float* Wsub  = (const float*)d_in[7];
  const float* Vo    = (const float*)d_in[8];
  const float* Theta = (const float*)d_in[9];
  const float* Whist = (const float*)d_in[10];
  float* ws = (float*)d_ws;
  float* out = (float*)d_out;
  float* outV  = out;                          // final_V: 20000 f32
  float* outNs = out + T_DATA;                 // ns_out: 300000 f32
  float* outF  = out + T_DATA + T_DATA * SUB;  // out_filters: 6200 f32

  int force = 0;
  if (ws_size < (size_t)WS_END * 4 + 1024) force = 3000;
  else if (out_size != 326200) force = 3500;
  if (force) {
    sentinel_kernel<<<1, 256, 0, stream>>>(outV, force);
    return;
  }

  prep_kernel<<<1, 256, 0, stream>>>(Cse, Csi, cosb, Wsyn, Wsub, Vo, Theta, Whist, ws, outF);
  pool_kernel<<<5000, 256, 0, stream>>>(Se, Si, ws);
  conv_tree_kernel<<<313, 256, 0, stream>>>(ws, outNs);
  scan_kernel<<<1, 64, 0, stream>>>(ws, outV);
}

// Round 19
// 757.680 us; speedup vs baseline: 4.7791x; 4.7791x over previous
//
#include <hip/hip_runtime.h>
#include <hip/hip_bf16.h>

// Cos_RootHist_GLM — f32 in/out (passing since round 10, absmax 0.125).
// R19: scan pipelining via EMPTY-ASM VALUE PINS + static two-bank rotation.
//   R13/R18: all loads live (volatile / full unroll) -> 256 VGPR spill.
//   R14/R15: loads remat'd at use -> no lookahead, LDS latency exposed.
//   R16/R17: hand s_waitcnt raced compiler-invisible pending regs -> wrong.
//   Now: plain loads (compiler inserts correct counted lgkmcnt) + 
//   asm volatile("" : "+v"(slot)) pins that fix placement without forcing
//   whole-loop liveness. Banks A/B alternate; distance = 4 pairs ~160cy.

#define DEVINL __device__ __forceinline__

using f32x4 = __attribute__((ext_vector_type(4))) float;

static constexpr int T_DATA = 20000;
static constexpr int N_E = 2000;
static constexpr int N_I = 500;
static constexpr int SUB = 15;
static constexpr int T_NO = 200;
static constexpr int NB = 19;

// ws layout (f32 offsets) — total 670720 f32 = 2.683 MB
static constexpr int EKT_OFF = 0;       // [200][16] e-kern transposed
static constexpr int IKT_OFF = 3200;    // [200][16]
static constexpr int HT_OFF  = 6400;    // 256
static constexpr int PRM_OFF = 6656;    // 0..14 wsub2, 16..30 theta, 33 scale, 34 vo
static constexpr int WE_OFF  = 6720;    // 2000
static constexpr int WI_OFF  = 8720;    // 500
static constexpr int IDXE_B  = 36880;   // byte off, 2000 uchar
static constexpr int IDXI_B  = 38880;   // byte off, 500 uchar
static constexpr int BT_OFF  = 9856;    // 20736 (zero-padded past 20000)
static constexpr int SYNE_OFF = 30720;  // [20000][16]
static constexpr int SYNI_OFF = 350720; // [20000][16]
static constexpr int WS_END  = 670720;

DEVINL float fast_exp2(float x) {
#if __has_builtin(__builtin_amdgcn_exp2f)
  return __builtin_amdgcn_exp2f(x);
#else
  return exp2f(x);
#endif
}
DEVINL float fast_log2(float x) {
#if __has_builtin(__builtin_amdgcn_logf)
  return __builtin_amdgcn_logf(x);
#else
  return log2f(x);
#endif
}
DEVINL float rlane(float v, int l) {
  return __builtin_bit_cast(float, __builtin_amdgcn_readlane(__builtin_bit_cast(int, v), l));
}

DEVINL float softplus_f(float x) {
  float z = x * 1.44269504088896f;
  float l = 0.6931471805599453f * fast_log2(1.0f + fast_exp2(z));
  return (x > 16.0f) ? x : l;
}

// ---------------- prep ----------------
__global__ __launch_bounds__(256) void prep_kernel(
    const float* __restrict__ Cse, const float* __restrict__ Csi,
    const float* __restrict__ cosb, const float* __restrict__ Wsyn,
    const float* __restrict__ Wsub, const float* __restrict__ Vo,
    const float* __restrict__ Theta, const float* __restrict__ Whist,
    float* __restrict__ ws, float* __restrict__ outF) {
  const int tid = threadIdx.x;
  float* ekT = ws + EKT_OFF;
  float* ikT = ws + IKT_OFF;
  float* ht  = ws + HT_OFF;
  float* prm = ws + PRM_OFF;
  float* we  = ws + WE_OFF;
  float* wi  = ws + WI_OFF;
  unsigned char* idxe = (unsigned char*)ws + IDXE_B;
  unsigned char* idxi = (unsigned char*)ws + IDXI_B;
  float* bT  = ws + BT_OFF;

  for (int p = tid; p < SUB * T_NO; p += 256) {
    int s = p / T_NO, j = p - s * T_NO;
    float ae = 0.f, ai = 0.f;
    for (int b = 0; b < NB; ++b) {
      float cb = cosb[b * T_NO + j];
      ae = fmaf(Wsyn[(s * NB + b) * 2 + 0], cb, ae);
      ai = fmaf(Wsyn[(s * NB + b) * 2 + 1], cb, ai);
    }
    ekT[j * 16 + s] = ae;
    ikT[j * 16 + s] = ai;
    outF[p] = ae;
    outF[SUB * T_NO + p] = ai;
  }
  for (int j = tid; j < T_NO; j += 256) { ekT[j * 16 + 15] = 0.f; ikT[j * 16 + 15] = 0.f; }
  if (tid < 256) {
    float hv = 0.f;
    if (tid < T_NO) {
      for (int b = 0; b < NB; ++b) hv = fmaf(Whist[b], cosb[b * T_NO + tid], hv);
      outF[30 * T_NO + tid] = hv;
    }
    ht[tid] = (tid < T_NO) ? hv : 0.f;   // ht[0] == hist[0] == 0 exactly
  }
  for (int n = tid; n < N_E; n += 256) {
    int id = 0; float w = 0.f;
    for (int s = 0; s < SUB; ++s) { float c = Cse[s * N_E + n]; if (c != 0.f) { id = s; w = c; } }
    idxe[n] = (unsigned char)id; we[n] = w;
  }
  for (int n = tid; n < N_I; n += 256) {
    int id = 0; float w = 0.f;
    for (int s = 0; s < SUB; ++s) { float c = Csi[s * N_I + n]; if (c != 0.f) { id = s; w = c; } }
    idxi[n] = (unsigned char)id; wi[n] = w;
  }
  if (tid < SUB) {
    float w = Wsub[tid];
    prm[tid] = w * w;
    prm[16 + tid] = Theta[tid];
  }
  if (tid == 0) {
    float w0 = Wsub[0];
    prm[33] = w0 * w0;
    prm[34] = Vo[0];
  }
  for (int p = T_DATA + tid; p < T_DATA + 736; p += 256) bT[p] = 0.f;
}

// ---------------- pool: wave per t-row, float4 loads, LDS atomics ----------------
__global__ __launch_bounds__(256) void pool_kernel(
    const float* __restrict__ Se, const float* __restrict__ Si,
    float* __restrict__ ws) {
  __shared__ float cnt[4][32];   // [wave][0:16 E | 16:32 I]
  const int lane = threadIdx.x & 63;
  const int w = threadIdx.x >> 6;
  const int t = blockIdx.x * 4 + w;
  if (lane < 32) cnt[w][lane] = 0.f;
  __syncthreads();
  const float* we = ws + WE_OFF;
  const float* wi = ws + WI_OFF;
  const unsigned int* ie = (const unsigned int*)((const char*)ws + IDXE_B);
  const unsigned int* ii = (const unsigned int*)((const char*)ws + IDXI_B);

  const float4* rowE = (const float4*)(Se + (size_t)t * N_E);   // 500 float4
#pragma unroll
  for (int k = 0; k < 8; ++k) {
    int c = k * 64 + lane;
    if (c < 500) {
      float4 v = rowE[c];
      unsigned int b = ie[c];
      if (v.x != 0.f) atomicAdd(&cnt[w][(b      ) & 0xFFu], v.x * we[c * 4 + 0]);
      if (v.y != 0.f) atomicAdd(&cnt[w][(b >>  8) & 0xFFu], v.y * we[c * 4 + 1]);
      if (v.z != 0.f) atomicAdd(&cnt[w][(b >> 16) & 0xFFu], v.z * we[c * 4 + 2]);
      if (v.w != 0.f) atomicAdd(&cnt[w][(b >> 24) & 0xFFu], v.w * we[c * 4 + 3]);
    }
  }
  const float4* rowI = (const float4*)(Si + (size_t)t * N_I);   // 125 float4
#pragma unroll
  for (int k = 0; k < 2; ++k) {
    int c = k * 64 + lane;
    if (c < 125) {
      float4 v = rowI[c];
      unsigned int b = ii[c];
      if (v.x != 0.f) atomicAdd(&cnt[w][16 + ((b      ) & 0xFFu)], v.x * wi[c * 4 + 0]);
      if (v.y != 0.f) atomicAdd(&cnt[w][16 + ((b >>  8) & 0xFFu)], v.y * wi[c * 4 + 1]);
      if (v.z != 0.f) atomicAdd(&cnt[w][16 + ((b >> 16) & 0xFFu)], v.z * wi[c * 4 + 2]);
      if (v.w != 0.f) atomicAdd(&cnt[w][16 + ((b >> 24) & 0xFFu)], v.w * wi[c * 4 + 3]);
    }
  }
  __syncthreads();
  if (lane < 16) {
    ws[SYNE_OFF + (size_t)t * 16 + lane] = cnt[w][lane];
    ws[SYNI_OFF + (size_t)t * 16 + lane] = cnt[w][16 + lane];
  }
}

// ---------------- conv + tree: transposed LDS tiles, conflict-free ----------------
__global__ __launch_bounds__(256) void conv_tree_kernel(float* __restrict__ ws,
                                                        float* __restrict__ outNs) {
  __shared__ float sE[16][272], sI[16][272];   // transposed, padded rows
  __shared__ float ekL[200 * 16], ikL[200 * 16];
  __shared__ float synR[64][16];
  const int tid = threadIdx.x;
  const int t0 = blockIdx.x * 64;

  for (int p = tid; p < 200 * 16; p += 256) { ekL[p] = ws[EKT_OFF + p]; ikL[p] = ws[IKT_OFF + p]; }
  for (int p = tid; p < 264 * 16; p += 256) {
    int o = p >> 4, s = p & 15;
    int g = t0 - 200 + o;
    bool ok = (g >= 0) && (g < T_DATA);
    sE[s][o] = ok ? ws[SYNE_OFF + (size_t)g * 16 + s] : 0.f;
    sI[s][o] = ok ? ws[SYNI_OFF + (size_t)g * 16 + s] : 0.f;
  }
  __syncthreads();
  {
    const int q = tid >> 6, i = tid & 63;
    const int s0 = q * 4;
    float ax = 0.f, ay = 0.f, az = 0.f, aw = 0.f;
    for (int j = 0; j < T_NO; ++j) {
      int o = i + 200 - j;
      float4 e = *(const float4*)&ekL[j * 16 + s0];   // wave-uniform: broadcast
      float4 k = *(const float4*)&ikL[j * 16 + s0];
      ax = fmaf(e.x, sE[s0 + 0][o], fmaf(k.x, sI[s0 + 0][o], ax));
      ay = fmaf(e.y, sE[s0 + 1][o], fmaf(k.y, sI[s0 + 1][o], ay));
      az = fmaf(e.z, sE[s0 + 2][o], fmaf(k.z, sI[s0 + 2][o], az));
      aw = fmaf(e.w, sE[s0 + 3][o], fmaf(k.w, sI[s0 + 3][o], aw));
    }
    synR[i][s0 + 0] = ax;
    synR[i][s0 + 1] = ay;
    synR[i][s0 + 2] = az;
    synR[i][s0 + 3] = aw;
  }
  __syncthreads();
  if (tid < 64) {
    int t = t0 + tid;
    if (t < T_DATA) {
      const float* prm = ws + PRM_OFF;
      float sv[16];
#pragma unroll
      for (int s = 0; s < 16; ++s) sv[s] = synR[tid][s];
      float ns[SUB];
#pragma unroll
      for (int j = SUB - 1; j >= 1; --j) {
        float x = sv[j] + prm[16 + j];
        if (2 * j + 1 < SUB) x = fmaf(prm[2 * j + 1], ns[2 * j + 1], x);
        if (2 * j + 2 < SUB) x = fmaf(prm[2 * j + 2], ns[2 * j + 2], x);
        ns[j] = softplus_f(x);
      }
      float b = sv[0] + prm[16];
      b = fmaf(prm[1], ns[1], b);
      b = fmaf(prm[2], ns[2], b);
      ws[BT_OFF + t] = b;
      outNs[(size_t)t * SUB] = 0.f;
#pragma unroll
      for (int s = 1; s < SUB; ++s) outNs[(size_t)t * SUB + s] = ns[s];
    }
  }
}

// ---------------- serial scan: pair-parallel ring-FIR, two-bank pinned pipeline ----------------
// rt4[u*4+r] = ht[(64r-1-u)&255] (u up to 352: formula wraps, tail prefetches
// are dead-but-in-bounds). Pair k consumes rows 2k,2k+1 (32B).
// Banks A/B of 8 f32x4; loads are PLAIN (compiler emits counted lgkmcnt);
// empty-asm pins fix placement without volatile's whole-loop liveness.
__global__ __launch_bounds__(64) void scan_kernel(const float* __restrict__ ws,
                                                  float* __restrict__ outV) {
  __shared__ __align__(16) float rt4[352 * 4];
  const int lane = threadIdx.x;
  const float* ht = ws + HT_OFF;
  const float* prm = ws + PRM_OFF;
  const float* bT = ws + BT_OFF;
  for (int p = lane; p < 352 * 4; p += 64) {
    int u = p >> 2, r = p & 3;
    rt4[p] = ht[(64 * r - 1 - u) & 255];
  }
  __syncthreads();
  const float L2E = 1.44269504088896f;
  const float scale2 = 0.6931471805599453f * prm[33];  // ln2 * wsub2[0]
  const float vo = prm[34];
  float a0 = L2E * bT[lane];          // fires in sub-chunks c==0
  float a1 = L2E * bT[64 + lane];     // c==1
  float a2 = L2E * bT[128 + lane];    // c==2
  float a3 = L2E * bT[192 + lane];    // c==3
  float cap = 0.f;
  const int myk = lane >> 1;
  const bool oddlane = (lane & 1);
  int ub = (0 - lane) & 255;
  int t0 = 0;

#define LOADBANK(B, PB)                                                          \
  B##0 = *(const f32x4*)(rp + ((PB) * 2 + 0) * 16);                              \
  B##1 = *(const f32x4*)(rp + ((PB) * 2 + 1) * 16);                              \
  B##2 = *(const f32x4*)(rp + ((PB) * 2 + 2) * 16);                              \
  B##3 = *(const f32x4*)(rp + ((PB) * 2 + 3) * 16);                              \
  B##4 = *(const f32x4*)(rp + ((PB) * 2 + 4) * 16);                              \
  B##5 = *(const f32x4*)(rp + ((PB) * 2 + 5) * 16);                              \
  B##6 = *(const f32x4*)(rp + ((PB) * 2 + 6) * 16);                              \
  B##7 = *(const f32x4*)(rp + ((PB) * 2 + 7) * 16);

#define PIN(B)                                                                   \
  asm volatile("" : "+v"(B##0), "+v"(B##1), "+v"(B##2), "+v"(B##3),              \
                    "+v"(B##4), "+v"(B##5), "+v"(B##6), "+v"(B##7));

#define PAIR(AC, K, C0, C1)                                                      \
  {                                                                              \
    float OB0 = rlane(AC, 2 * (K));                                              \
    float OB1 = rlane(AC, 2 * (K) + 1);                                          \
    float y0 = fast_log2(1.0f + fast_exp2(OB0));                                 \
    float y1 = fast_log2(1.0f + fast_exp2(OB1));                                 \
    bool own = (myk == (K));                                                     \
    cap = own ? (oddlane ? y1 : y0) : cap;                                       \
    AC = own ? bnext : AC;                                                       \
    a0 = fmaf(C0[0], y0, a0); a0 = fmaf(C1[0], y1, a0);                          \
    a1 = fmaf(C0[1], y0, a1); a1 = fmaf(C1[1], y1, a1);                          \
    a2 = fmaf(C0[2], y0, a2); a2 = fmaf(C1[2], y1, a2);                          \
    a3 = fmaf(C0[3], y0, a3); a3 = fmaf(C1[3], y1, a3);                          \
  }

#define CONSUME4(AC, KB, G)                                                      \
  PAIR(AC, (KB) + 0, G##0, G##1)                                                 \
  PAIR(AC, (KB) + 1, G##2, G##3)                                                 \
  PAIR(AC, (KB) + 2, G##4, G##5)                                                 \
  PAIR(AC, (KB) + 3, G##6, G##7)

#define SUBCHUNK(AC, BN)                                                         \
  {                                                                              \
    const float bnext = (BN);                                                    \
    const char* rp = (const char*)rt4 + (size_t)((unsigned)ub * 16u);            \
    f32x4 A0, A1, A2, A3, A4, A5, A6, A7;                                        \
    f32x4 B0, B1, B2, B3, B4, B5, B6, B7;                                        \
    LOADBANK(A, 0)                                                               \
    PIN(A)                                                                       \
    int kb = 0;                                                                  \
    _Pragma("unroll 1")                                                          \
    for (int j = 0; j < 4; ++j) {                                                \
      LOADBANK(B, kb + 4)                                                        \
      PIN(B)                                                                     \
      CONSUME4(AC, kb, A)                                                        \
      LOADBANK(A, kb + 8)                                                        \
      PIN(A)                                                                     \
      CONSUME4(AC, kb + 4, B)                                                    \
      kb += 8;                                                                   \
    }                                                                            \
    int t = t0 + lane;                                                           \
    if (t < T_DATA) outV[t] = fmaf(cap, scale2, vo);                             \
    ub = (ub + 64) & 255;                                                        \
    t0 += 64;                                                                    \
  }

#pragma unroll 1
  for (int g = 0; g < 78; ++g) {   // 312 chunks
    const float bn0 = L2E * bT[t0 + 256 + lane];
    const float bn1 = L2E * bT[t0 + 320 + lane];
    const float bn2 = L2E * bT[t0 + 384 + lane];
    const float bn3 = L2E * bT[t0 + 448 + lane];
    SUBCHUNK(a0, bn0)
    SUBCHUNK(a1, bn1)
    SUBCHUNK(a2, bn2)
    SUBCHUNK(a3, bn3)
  }
  {
    const float bnT = L2E * bT[t0 + 256 + lane];
    SUBCHUNK(a0, bnT)               // chunk 312 (t0 = 19968)
  }
#undef PAIR
#undef CONSUME4
#undef SUBCHUNK
#undef LOADBANK
#undef PIN
}

// ---------------- sentinel ----------------
__global__ __launch_bounds__(256) void sentinel_kernel(float* __restrict__ outV, int code) {
  const int tid = threadIdx.x;
  for (int t = tid; t < T_DATA; t += 256) outV[t] = (float)code;
}

extern "C" void kernel_launch(void* const* d_in, const int* in_sizes, int n_in,
                              void* d_out, int out_size, void* d_ws, size_t ws_size,
                              hipStream_t stream) {
  const float* Se    = (const float*)d_in[0];
  const float* Si    = (const float*)d_in[1];
  const float* Cse   = (const float*)d_in[3];
  const float* Csi   = (const float*)d_in[4];
  const float* cosb  = (const float*)d_in[5];
  const float* Wsyn  = (const float*)d_in[6];
  const float* Wsub  = (const float*)d_in[7];
  const float* Vo    = (const float*)d_in[8];
  const float* Theta = (const float*)d_in[9];
  const float* Whist = (const float*)d_in[10];
  float* ws = (float*)d_ws;
  float* out = (float*)d_out;
  float* outV  = out;                          // final_V: 20000 f32
  float* outNs = out + T_DATA;                 // ns_out: 300000 f32
  float* outF  = out + T_DATA + T_DATA * SUB;  // out_filters: 6200 f32

  int force = 0;
  if (ws_size < (size_t)WS_END * 4 + 1024) force = 3000;
  else if (out_size != 326200) force = 3500;
  if (force) {
    sentinel_kernel<<<1, 256, 0, stream>>>(outV, force);
    return;
  }

  prep_kernel<<<1, 256, 0, stream>>>(Cse, Csi, cosb, Wsyn, Wsub, Vo, Theta, Whist, ws, outF);
  pool_kernel<<<5000, 256, 0, stream>>>(Se, Si, ws);
  conv_tree_kernel<<<313, 256, 0, stream>>>(ws, outNs);
  scan_kernel<<<1, 64, 0, stream>>>(ws, outV);
}

// Round 20
// 650.846 us; speedup vs baseline: 5.5636x; 1.1641x over previous
//
#include <hip/hip_runtime.h>
#include <hip/hip_bf16.h>

// Cos_RootHist_GLM — f32 in/out (passing since round 10, absmax 0.125).
// R20: scan restructured so the SERIAL path uses only REGISTER coefficients.
//   Role-relative coefficient ht[(l-i-1+64*rho)&255] is CHUNK-INVARIANT:
//   rho=0 (firing) -> 64 per-lane values preloaded ONCE into VGPRs (csr);
//   rho=1..3 -> deferred end-of-chunk 64x64 Toeplitz matvecs on Y=cap
//   (dependency-free; LDS b128 from 4-way phase-replicated table, aligned).
//   FP order per register identical to R12 -> absmax stays exactly 0.125.

#define DEVINL __device__ __forceinline__

using f32x4 = __attribute__((ext_vector_type(4))) float;

static constexpr int T_DATA = 20000;
static constexpr int N_E = 2000;
static constexpr int N_I = 500;
static constexpr int SUB = 15;
static constexpr int T_NO = 200;
static constexpr int NB = 19;

// ws layout (f32 offsets) — total 670720 f32 = 2.683 MB
static constexpr int EKT_OFF = 0;       // [200][16] e-kern transposed
static constexpr int IKT_OFF = 3200;    // [200][16]
static constexpr int HT_OFF  = 6400;    // 256 (zeroed >=200)
static constexpr int PRM_OFF = 6656;    // 0..14 wsub2, 16..30 theta, 33 scale, 34 vo
static constexpr int WE_OFF  = 6720;    // 2000
static constexpr int WI_OFF  = 8720;    // 500
static constexpr int IDXE_B  = 36880;   // byte off, 2000 uchar
static constexpr int IDXI_B  = 38880;   // byte off, 500 uchar
static constexpr int BT_OFF  = 9856;    // 20736 (zero-padded past 20000)
static constexpr int SYNE_OFF = 30720;  // [20000][16]
static constexpr int SYNI_OFF = 350720; // [20000][16]
static constexpr int WS_END  = 670720;

DEVINL float fast_exp2(float x) {
#if __has_builtin(__builtin_amdgcn_exp2f)
  return __builtin_amdgcn_exp2f(x);
#else
  return exp2f(x);
#endif
}
DEVINL float fast_log2(float x) {
#if __has_builtin(__builtin_amdgcn_logf)
  return __builtin_amdgcn_logf(x);
#else
  return log2f(x);
#endif
}
DEVINL float rlane(float v, int l) {
  return __builtin_bit_cast(float, __builtin_amdgcn_readlane(__builtin_bit_cast(int, v), l));
}

DEVINL float softplus_f(float x) {
  float z = x * 1.44269504088896f;
  float l = 0.6931471805599453f * fast_log2(1.0f + fast_exp2(z));
  return (x > 16.0f) ? x : l;
}

// ---------------- prep ----------------
__global__ __launch_bounds__(256) void prep_kernel(
    const float* __restrict__ Cse, const float* __restrict__ Csi,
    const float* __restrict__ cosb, const float* __restrict__ Wsyn,
    const float* __restrict__ Wsub, const float* __restrict__ Vo,
    const float* __restrict__ Theta, const float* __restrict__ Whist,
    float* __restrict__ ws, float* __restrict__ outF) {
  const int tid = threadIdx.x;
  float* ekT = ws + EKT_OFF;
  float* ikT = ws + IKT_OFF;
  float* ht  = ws + HT_OFF;
  float* prm = ws + PRM_OFF;
  float* we  = ws + WE_OFF;
  float* wi  = ws + WI_OFF;
  unsigned char* idxe = (unsigned char*)ws + IDXE_B;
  unsigned char* idxi = (unsigned char*)ws + IDXI_B;
  float* bT  = ws + BT_OFF;

  for (int p = tid; p < SUB * T_NO; p += 256) {
    int s = p / T_NO, j = p - s * T_NO;
    float ae = 0.f, ai = 0.f;
    for (int b = 0; b < NB; ++b) {
      float cb = cosb[b * T_NO + j];
      ae = fmaf(Wsyn[(s * NB + b) * 2 + 0], cb, ae);
      ai = fmaf(Wsyn[(s * NB + b) * 2 + 1], cb, ai);
    }
    ekT[j * 16 + s] = ae;
    ikT[j * 16 + s] = ai;
    outF[p] = ae;
    outF[SUB * T_NO + p] = ai;
  }
  for (int j = tid; j < T_NO; j += 256) { ekT[j * 16 + 15] = 0.f; ikT[j * 16 + 15] = 0.f; }
  if (tid < 256) {
    float hv = 0.f;
    if (tid < T_NO) {
      for (int b = 0; b < NB; ++b) hv = fmaf(Whist[b], cosb[b * T_NO + tid], hv);
      outF[30 * T_NO + tid] = hv;
    }
    ht[tid] = (tid < T_NO) ? hv : 0.f;   // ht[0] == hist[0] == 0 exactly; zero 200..255
  }
  for (int n = tid; n < N_E; n += 256) {
    int id = 0; float w = 0.f;
    for (int s = 0; s < SUB; ++s) { float c = Cse[s * N_E + n]; if (c != 0.f) { id = s; w = c; } }
    idxe[n] = (unsigned char)id; we[n] = w;
  }
  for (int n = tid; n < N_I; n += 256) {
    int id = 0; float w = 0.f;
    for (int s = 0; s < SUB; ++s) { float c = Csi[s * N_I + n]; if (c != 0.f) { id = s; w = c; } }
    idxi[n] = (unsigned char)id; wi[n] = w;
  }
  if (tid < SUB) {
    float w = Wsub[tid];
    prm[tid] = w * w;
    prm[16 + tid] = Theta[tid];
  }
  if (tid == 0) {
    float w0 = Wsub[0];
    prm[33] = w0 * w0;
    prm[34] = Vo[0];
  }
  for (int p = T_DATA + tid; p < T_DATA + 736; p += 256) bT[p] = 0.f;
}

// ---------------- pool: wave per t-row, float4 loads, LDS atomics ----------------
__global__ __launch_bounds__(256) void pool_kernel(
    const float* __restrict__ Se, const float* __restrict__ Si,
    float* __restrict__ ws) {
  __shared__ float cnt[4][32];   // [wave][0:16 E | 16:32 I]
  const int lane = threadIdx.x & 63;
  const int w = threadIdx.x >> 6;
  const int t = blockIdx.x * 4 + w;
  if (lane < 32) cnt[w][lane] = 0.f;
  __syncthreads();
  const float* we = ws + WE_OFF;
  const float* wi = ws + WI_OFF;
  const unsigned int* ie = (const unsigned int*)((const char*)ws + IDXE_B);
  const unsigned int* ii = (const unsigned int*)((const char*)ws + IDXI_B);

  const float4* rowE = (const float4*)(Se + (size_t)t * N_E);   // 500 float4
#pragma unroll
  for (int k = 0; k < 8; ++k) {
    int c = k * 64 + lane;
    if (c < 500) {
      float4 v = rowE[c];
      unsigned int b = ie[c];
      if (v.x != 0.f) atomicAdd(&cnt[w][(b      ) & 0xFFu], v.x * we[c * 4 + 0]);
      if (v.y != 0.f) atomicAdd(&cnt[w][(b >>  8) & 0xFFu], v.y * we[c * 4 + 1]);
      if (v.z != 0.f) atomicAdd(&cnt[w][(b >> 16) & 0xFFu], v.z * we[c * 4 + 2]);
      if (v.w != 0.f) atomicAdd(&cnt[w][(b >> 24) & 0xFFu], v.w * we[c * 4 + 3]);
    }
  }
  const float4* rowI = (const float4*)(Si + (size_t)t * N_I);   // 125 float4
#pragma unroll
  for (int k = 0; k < 2; ++k) {
    int c = k * 64 + lane;
    if (c < 125) {
      float4 v = rowI[c];
      unsigned int b = ii[c];
      if (v.x != 0.f) atomicAdd(&cnt[w][16 + ((b      ) & 0xFFu)], v.x * wi[c * 4 + 0]);
      if (v.y != 0.f) atomicAdd(&cnt[w][16 + ((b >>  8) & 0xFFu)], v.y * wi[c * 4 + 1]);
      if (v.z != 0.f) atomicAdd(&cnt[w][16 + ((b >> 16) & 0xFFu)], v.z * wi[c * 4 + 2]);
      if (v.w != 0.f) atomicAdd(&cnt[w][16 + ((b >> 24) & 0xFFu)], v.w * wi[c * 4 + 3]);
    }
  }
  __syncthreads();
  if (lane < 16) {
    ws[SYNE_OFF + (size_t)t * 16 + lane] = cnt[w][lane];
    ws[SYNI_OFF + (size_t)t * 16 + lane] = cnt[w][16 + lane];
  }
}

// ---------------- conv + tree: transposed LDS tiles, conflict-free ----------------
__global__ __launch_bounds__(256) void conv_tree_kernel(float* __restrict__ ws,
                                                        float* __restrict__ outNs) {
  __shared__ float sE[16][272], sI[16][272];   // transposed, padded rows
  __shared__ float ekL[200 * 16], ikL[200 * 16];
  __shared__ float synR[64][16];
  const int tid = threadIdx.x;
  const int t0 = blockIdx.x * 64;

  for (int p = tid; p < 200 * 16; p += 256) { ekL[p] = ws[EKT_OFF + p]; ikL[p] = ws[IKT_OFF + p]; }
  for (int p = tid; p < 264 * 16; p += 256) {
    int o = p >> 4, s = p & 15;
    int g = t0 - 200 + o;
    bool ok = (g >= 0) && (g < T_DATA);
    sE[s][o] = ok ? ws[SYNE_OFF + (size_t)g * 16 + s] : 0.f;
    sI[s][o] = ok ? ws[SYNI_OFF + (size_t)g * 16 + s] : 0.f;
  }
  __syncthreads();
  {
    const int q = tid >> 6, i = tid & 63;
    const int s0 = q * 4;
    float ax = 0.f, ay = 0.f, az = 0.f, aw = 0.f;
    for (int j = 0; j < T_NO; ++j) {
      int o = i + 200 - j;
      float4 e = *(const float4*)&ekL[j * 16 + s0];   // wave-uniform: broadcast
      float4 k = *(const float4*)&ikL[j * 16 + s0];
      ax = fmaf(e.x, sE[s0 + 0][o], fmaf(k.x, sI[s0 + 0][o], ax));
      ay = fmaf(e.y, sE[s0 + 1][o], fmaf(k.y, sI[s0 + 1][o], ay));
      az = fmaf(e.z, sE[s0 + 2][o], fmaf(k.z, sI[s0 + 2][o], az));
      aw = fmaf(e.w, sE[s0 + 3][o], fmaf(k.w, sI[s0 + 3][o], aw));
    }
    synR[i][s0 + 0] = ax;
    synR[i][s0 + 1] = ay;
    synR[i][s0 + 2] = az;
    synR[i][s0 + 3] = aw;
  }
  __syncthreads();
  if (tid < 64) {
    int t = t0 + tid;
    if (t < T_DATA) {
      const float* prm = ws + PRM_OFF;
      float sv[16];
#pragma unroll
      for (int s = 0; s < 16; ++s) sv[s] = synR[tid][s];
      float ns[SUB];
#pragma unroll
      for (int j = SUB - 1; j >= 1; --j) {
        float x = sv[j] + prm[16 + j];
        if (2 * j + 1 < SUB) x = fmaf(prm[2 * j + 1], ns[2 * j + 1], x);
        if (2 * j + 2 < SUB) x = fmaf(prm[2 * j + 2], ns[2 * j + 2], x);
        ns[j] = softplus_f(x);
      }
      float b = sv[0] + prm[16];
      b = fmaf(prm[1], ns[1], b);
      b = fmaf(prm[2], ns[2], b);
      ws[BT_OFF + t] = b;
      outNs[(size_t)t * SUB] = 0.f;
#pragma unroll
      for (int s = 1; s < SUB; ++s) outNs[(size_t)t * SUB + s] = ns[s];
    }
  }
}

// ---------------- serial scan: role-relative split ----------------
// Serial phase (firing register only): coefficient csr[63-i] = ht[(lane-i-1)&255],
// preloaded ONCE into 64 VGPRs -> zero memory ops on the serial path.
// Deferred phase: R_rho[l] += sum_i ht[l-i-1+64*rho] * Y[i], rho=1..3 —
// Toeplitz matvecs on Y=cap, LDS b128 from 4-way phase-replicated table.
__global__ __launch_bounds__(64) void scan_kernel(const float* __restrict__ ws,
                                                  float* __restrict__ outV) {
  __shared__ float tP[128];                      // tP[j] = ht[(j+192)&255]
  __shared__ __align__(16) float mtc[4][264];    // mtc[p][m] = ht[m+p] (0 past 255)
  const int lane = threadIdx.x;
  const float* ht = ws + HT_OFF;
  const float* prm = ws + PRM_OFF;
  const float* bT = ws + BT_OFF;
  for (int j = lane; j < 128; j += 64) tP[j] = ht[(j + 192) & 255];
  for (int p0 = lane; p0 < 4 * 264; p0 += 64) {
    int p = p0 / 264, m = p0 - p * 264;
    mtc[p][m] = (m + p < 256) ? ht[m + p] : 0.f;
  }
  __syncthreads();

  // per-lane serial coefficients: csr[j] = ht[(lane - 64 + j) & 255]; cs(i)=csr[63-i]
  float csr[64];
#pragma unroll
  for (int j = 0; j < 64; ++j) csr[j] = tP[lane + j];

  const float L2E = 1.44269504088896f;
  const float scale2 = 0.6931471805599453f * prm[33];  // ln2 * wsub2[0]
  const float vo = prm[34];
  float a0 = L2E * bT[lane];
  float a1 = L2E * bT[64 + lane];
  float a2 = L2E * bT[128 + lane];
  float a3 = L2E * bT[192 + lane];
  float cap = 0.f;
  const int myk = lane >> 1;
  const bool oddlane = (lane & 1);
  int t0 = 0;
  const float* mbase = &mtc[lane & 3][lane & ~3];  // 16B-aligned per lane

#define SPAIR(AC, K)                                                             \
  {                                                                              \
    float OB0 = rlane(AC, 2 * (K));                                              \
    float OB1 = rlane(AC, 2 * (K) + 1);                                          \
    float y0 = fast_log2(1.0f + fast_exp2(OB0));                                 \
    float y1 = fast_log2(1.0f + fast_exp2(OB1));                                 \
    bool own = (myk == (K));                                                     \
    cap = own ? (oddlane ? y1 : y0) : cap;                                       \
    AC = own ? bnext : AC;                                                       \
    AC = fmaf(csr[63 - 2 * (K)], y0, AC);                                        \
    AC = fmaf(csr[62 - 2 * (K)], y1, AC);                                        \
  }

#define SP8(AC, K)                                                               \
  SPAIR(AC, (K) + 0) SPAIR(AC, (K) + 1) SPAIR(AC, (K) + 2) SPAIR(AC, (K) + 3)    \
  SPAIR(AC, (K) + 4) SPAIR(AC, (K) + 5) SPAIR(AC, (K) + 6) SPAIR(AC, (K) + 7)

#define MVB(IB, R1, R2, R3)                                                      \
  {                                                                              \
    float yb0 = rlane(cap, (IB) + 0);                                            \
    float yb1 = rlane(cap, (IB) + 1);                                            \
    float yb2 = rlane(cap, (IB) + 2);                                            \
    float yb3 = rlane(cap, (IB) + 3);                                            \
    f32x4 c1 = *(const f32x4*)(mbase + (60 - (IB)));                             \
    f32x4 c2 = *(const f32x4*)(mbase + (124 - (IB)));                            \
    f32x4 c3 = *(const f32x4*)(mbase + (188 - (IB)));                            \
    R1 = fmaf(c1[3], yb0, R1); R1 = fmaf(c1[2], yb1, R1);                        \
    R1 = fmaf(c1[1], yb2, R1); R1 = fmaf(c1[0], yb3, R1);                        \
    R2 = fmaf(c2[3], yb0, R2); R2 = fmaf(c2[2], yb1, R2);                        \
    R2 = fmaf(c2[1], yb2, R2); R2 = fmaf(c2[0], yb3, R2);                        \
    R3 = fmaf(c3[3], yb0, R3); R3 = fmaf(c3[2], yb1, R3);                        \
    R3 = fmaf(c3[1], yb2, R3); R3 = fmaf(c3[0], yb3, R3);                        \
  }

#define SUBCHUNK(AC, R1, R2, R3, BN)                                             \
  {                                                                              \
    const float bnext = (BN);                                                    \
    SP8(AC, 0) SP8(AC, 8) SP8(AC, 16) SP8(AC, 24)                                \
    int t = t0 + lane;                                                           \
    if (t < T_DATA) outV[t] = fmaf(cap, scale2, vo);                             \
    MVB(0, R1, R2, R3)  MVB(4, R1, R2, R3)  MVB(8, R1, R2, R3)                   \
    MVB(12, R1, R2, R3) MVB(16, R1, R2, R3) MVB(20, R1, R2, R3)                  \
    MVB(24, R1, R2, R3) MVB(28, R1, R2, R3) MVB(32, R1, R2, R3)                  \
    MVB(36, R1, R2, R3) MVB(40, R1, R2, R3) MVB(44, R1, R2, R3)                  \
    MVB(48, R1, R2, R3) MVB(52, R1, R2, R3) MVB(56, R1, R2, R3)                  \
    MVB(60, R1, R2, R3)                                                          \
    t0 += 64;                                                                    \
  }

#pragma unroll 1
  for (int g = 0; g < 78; ++g) {   // 312 chunks
    const float bn0 = L2E * bT[t0 + 256 + lane];
    const float bn1 = L2E * bT[t0 + 320 + lane];
    const float bn2 = L2E * bT[t0 + 384 + lane];
    const float bn3 = L2E * bT[t0 + 448 + lane];
    SUBCHUNK(a0, a1, a2, a3, bn0)
    SUBCHUNK(a1, a2, a3, a0, bn1)
    SUBCHUNK(a2, a3, a0, a1, bn2)
    SUBCHUNK(a3, a0, a1, a2, bn3)
  }
  {
    const float bnT = L2E * bT[t0 + 256 + lane];
    SUBCHUNK(a0, a1, a2, a3, bnT)   // chunk 312 (t0 = 19968)
  }
#undef SPAIR
#undef SP8
#undef MVB
#undef SUBCHUNK
}

// ---------------- sentinel ----------------
__global__ __launch_bounds__(256) void sentinel_kernel(float* __restrict__ outV, int code) {
  const int tid = threadIdx.x;
  for (int t = tid; t < T_DATA; t += 256) outV[t] = (float)code;
}

extern "C" void kernel_launch(void* const* d_in, const int* in_sizes, int n_in,
                              void* d_out, int out_size, void* d_ws, size_t ws_size,
                              hipStream_t stream) {
  const float* Se    = (const float*)d_in[0];
  const float* Si    = (const float*)d_in[1];
  const float* Cse   = (const float*)d_in[3];
  const float* Csi   = (const float*)d_in[4];
  const float* cosb  = (const float*)d_in[5];
  const float* Wsyn  = (const float*)d_in[6];
  const float* Wsub  = (const float*)d_in[7];
  const float* Vo    = (const float*)d_in[8];
  const float* Theta = (const float*)d_in[9];
  const float* Whist = (const float*)d_in[10];
  float* ws = (float*)d_ws;
  float* out = (float*)d_out;
  float* outV  = out;                          // final_V: 20000 f32
  float* outNs = out + T_DATA;                 // ns_out: 300000 f32
  float* outF  = out + T_DATA + T_DATA * SUB;  // out_filters: 6200 f32

  int force = 0;
  if (ws_size < (size_t)WS_END * 4 + 1024) force = 3000;
  else if (out_size != 326200) force = 3500;
  if (force) {
    sentinel_kernel<<<1, 256, 0, stream>>>(outV, force);
    return;
  }

  prep_kernel<<<1, 256, 0, stream>>>(Cse, Csi, cosb, Wsyn, Wsub, Vo, Theta, Whist, ws, outF);
  pool_kernel<<<5000, 256, 0, stream>>>(Se, Si, ws);
  conv_tree_kernel<<<313, 256, 0, stream>>>(ws, outNs);
  scan_kernel<<<1, 64, 0, stream>>>(ws, outV);
}